// Round 4
// baseline (455.164 us; speedup 1.0000x reference)
//
#include <hip/hip_runtime.h>

typedef _Float16 f16x8 __attribute__((ext_vector_type(8)));
typedef _Float16 f16x2 __attribute__((ext_vector_type(2)));
typedef float    f32x4 __attribute__((ext_vector_type(4)));

#define CIN    16
#define COUT   64
#define H      256
#define W      256
#define OH     254
#define OW     254
#define TH     32
#define TW     32
#define IN_H   (TH + 2)
#define IN_W   (TW + 2)
#define IN_PIX (IN_H * IN_W)
#define U_LOW  (18 * 8 * 9)            // 1296 staging units, input rows 0..17
#define U_ALL  (IN_H * 8 * 9)          // 2448 staging units total

// tanh(x) = 1 - 2/(e^{2x}+1): robust at +-inf
__device__ __forceinline__ float ftanh(float x) {
  float e = __expf(x + x);
  float r = __builtin_amdgcn_rcpf(e + 1.0f);
  return 1.0f - (r + r);
}

__device__ __forceinline__ f32x4 vmin4(f32x4 a, f32x4 b) {
  f32x4 r;
  r[0] = fminf(a[0], b[0]); r[1] = fminf(a[1], b[1]);
  r[2] = fminf(a[2], b[2]); r[3] = fminf(a[3], b[3]);
  return r;
}

// ---- one-time weight redistribution into workspace ----
// layout: [tap 0..9][cout 0..63][ci 0..15] f16.
// taps 0..8 = conv weights; tap 9 = bias row: [cout][0] = bias[cout], else 0.
// The matching B-operand for the tap-9 k-slots is the constant {1,0,...,0}
// (supplied from a register in the main kernel), so bias rides the MFMA and
// the per-wave binit[4] (16 AGPRs) disappears.
__global__ __launch_bounds__(256, 1)
void weight_prep(const float* __restrict__ wgt, const float* __restrict__ bias,
                 _Float16* __restrict__ ws) {
  const int t = threadIdx.x;
  // zero tap-9 row: 64*16 f16 = 512 dwords
  uint32_t* wz = (uint32_t*)(ws + 9 * COUT * 16);
  wz[t] = 0u; wz[t + 256] = 0u;
  __syncthreads();
  if (t < COUT) ws[(9 * COUT + t) * 16] = (_Float16)bias[t];
  // coalesced dwordx4 read of [cout][cin][tap] f32, scatter-store as f16
  const f32x4* w4 = (const f32x4*)wgt;   // 9216 floats, 36 per thread
#pragma unroll
  for (int k = 0; k < 9; ++k) {
    const f32x4 v = w4[9 * t + k];
#pragma unroll
    for (int e = 0; e < 4; ++e) {
      const int g   = (9 * t + k) * 4 + e;
      const int co  = g / 144;
      const int r   = g - 144 * co;
      const int ci  = r / 9;
      const int tap = r - 9 * ci;
      ws[(tap * COUT + co) * 16 + ci] = (_Float16)v[e];   // taps 0..8 only
    }
  }
}

__global__ __launch_bounds__(256, 4)
void conv_min_tanh_mfma(const float* __restrict__ x, const _Float16* __restrict__ ws,
                        float* __restrict__ out) {
  // input tile, fp16, interleaved [pixel][cin]: 34*34*16*2 = 36,992 B
  __shared__ __align__(16) _Float16 xs[IN_PIX * CIN];

  const int t   = threadIdx.x;
  const int b   = blockIdx.z;
  const int ow0 = blockIdx.x * TW;
  const int oh0 = blockIdx.y * TH;

  const int lane = t & 63;
  const int ln   = lane & 15;
  const int q    = lane >> 4;
  const int qh   = q >> 1;
  const int ql   = q & 1;
  const int wv   = t >> 6;

  // ---- A-fragments: 20 x 16B global loads, L2-broadcast ----
  // A[m=cout][k], lane holds cout = mt*16+ln, k = s*32 + q*8 + j,
  // K order: k = tap*16 + ci (tap = kh*3+kw); tap 9 = bias row.
  f16x8 wf[5][4];
#pragma unroll
  for (int s = 0; s < 5; ++s) {
    const int tap = 2 * s + qh;            // 0..9
#pragma unroll
    for (int mt = 0; mt < 4; ++mt) {
      const int cout = mt * 16 + ln;
      wf[s][mt] = *(const f16x8*)(ws + (tap * COUT + cout) * 16 + ql * 8);
    }
  }

  // constant B-frag for the bias k-slots (s=4, qh=1 lanes):
  // q==2 (ci 0..7) -> {1,0,...,0}; q==3 (ci 8..15) -> all zeros.
  f16x8 cst = {};
  if (q == 2) cst[0] = (_Float16)1.0f;

  // per-lane LDS element offset per K-step (qh=1 s=4 lanes use cst instead)
  int xoff[5];
#pragma unroll
  for (int s = 0; s < 5; ++s) {
    int tap = 2 * s + qh;
    if (tap > 8) tap = 8;                  // keep address in-bounds (unused)
    const int kh = tap / 3;
    const int kw = tap - kh * 3;
    xoff[s] = (kh * IN_W + kw) * CIN + ql * 8;
  }

  // ---- staging machinery: depth-2 software pipeline ----
  // unit u = (row*8 + cp)*9 + j: lane loads 4 consecutive pixels of
  // channels 2cp,2cp+1 (two dwordx4), packs 4 f16x2 -> LDS interleaved.
  f32x4 sv0[2], sv1[2];
  int   sbase[2], sj[2];
  bool  sact[2];

  auto prep = [&](int u, int uend, int slot) {
    const bool act = (u < uend);
    const int  s   = u / 9;
    const int  j   = u - 9 * s;
    const int  row = s >> 3;
    const int  cp  = s & 7;
    const int  ih  = oh0 + row;
    const int  iw0 = ow0 + 4 * j;
    const f32x4 z = {0.f, 0.f, 0.f, 0.f};
    sv0[slot] = z; sv1[slot] = z;
    if (act && ih < H && iw0 + 3 < W) {
      const float* p = x + (((size_t)b * CIN + 2 * cp) * H + ih) * W + iw0;
      sv0[slot] = *(const f32x4*)p;
      sv1[slot] = *(const f32x4*)(p + H * W);
    }
    sbase[slot] = (row * IN_W + 4 * j) * CIN + 2 * cp;
    sj[slot]    = j;
    sact[slot]  = act;
  };
  auto flush = [&](int slot) {
    if (sact[slot]) {
      const int base = sbase[slot];
      const int j    = sj[slot];
#pragma unroll
      for (int e = 0; e < 4; ++e) {
        if (4 * j + e < IN_W) {  // drop cols 34,35 of the j==8 over-read
          f16x2 h;
          h[0] = (_Float16)sv0[slot][e];
          h[1] = (_Float16)sv1[slot][e];
          *(f16x2*)(&xs[base + e * CIN]) = h;
        }
      }
    }
  };

  // compute 8 output rows (this wave's strip): rows wv*8 .. wv*8+7
  auto compute8 = [&]() {
    for (int rr = 0; rr < 8; ++rr) {
      const int row = wv * 8 + rr;
#pragma unroll
      for (int ct = 0; ct < 2; ++ct) {
        const int base_idx = (row * IN_W + ct * 16 + ln) * CIN;
        f32x4 a0 = {}, a1 = {}, a2 = {}, a3 = {};
#pragma unroll
        for (int s = 0; s < 5; ++s) {
          f16x8 xf;
          if (s == 4 && qh == 1) xf = cst;   // bias k-slots
          else xf = *(const f16x8*)(&xs[base_idx + xoff[s]]);  // ds_read_b128
          a0 = __builtin_amdgcn_mfma_f32_16x16x32_f16(wf[s][0], xf, a0, 0, 0, 0);
          a1 = __builtin_amdgcn_mfma_f32_16x16x32_f16(wf[s][1], xf, a1, 0, 0, 0);
          a2 = __builtin_amdgcn_mfma_f32_16x16x32_f16(wf[s][2], xf, a2, 0, 0, 0);
          a3 = __builtin_amdgcn_mfma_f32_16x16x32_f16(wf[s][3], xf, a3, 0, 0, 0);
        }
        // min over 64 couts: 4 m-tiles x 4 regs in-lane, then across quads
        f32x4 m4 = vmin4(vmin4(a0, a1), vmin4(a2, a3));
        float v = fminf(fminf(m4[0], m4[1]), fminf(m4[2], m4[3]));
        v = fminf(v, __shfl_xor(v, 16));
        v = fminf(v, __shfl_xor(v, 32));
        v = ftanh(ftanh(v));
        const int oh = oh0 + row;
        const int ow = ow0 + ct * 16 + ln;
        if (q == 0 && oh < OH && ow < OW)
          out[((size_t)b * OH + oh) * OW + ow] = v;   // 16 lanes, 64B coalesced
      }
    }
  };

  // ---- phase A: ALL waves stage input rows 0..17 (units [0, U_LOW)) ----
  prep(t, U_LOW, 0);
#pragma unroll
  for (int i = 0; i < 6; ++i) {
    if (i < 5) prep(t + 256 * (i + 1), U_LOW, (i + 1) & 1);
    flush(i & 1);
  }
  __syncthreads();   // barrier 1 (uniform): rows 0..17 staged

  // ---- phase B: waves 0,1 compute rows 0..15 (need inputs 0..17)
  //              waves 2,3 stage rows 18..33 -> HBM busy under compute ----
  if (wv < 2) {
    compute8();
  } else {
    const int tb = t - 128;
    prep(U_LOW + tb, U_ALL, 0);
#pragma unroll
    for (int i = 0; i < 9; ++i) {
      if (i < 8) prep(U_LOW + tb + 128 * (i + 1), U_ALL, (i + 1) & 1);
      flush(i & 1);
    }
  }
  __syncthreads();   // barrier 2 (uniform): rows 18..33 staged

  // ---- phase C: waves 2,3 compute rows 16..31; waves 0,1 exit early ----
  if (wv >= 2) compute8();
}

extern "C" void kernel_launch(void* const* d_in, const int* in_sizes, int n_in,
                              void* d_out, int out_size, void* d_ws, size_t ws_size,
                              hipStream_t stream) {
  const float* x    = (const float*)d_in[0];
  const float* wgt  = (const float*)d_in[1];  // [64][16][3][3]
  const float* bias = (const float*)d_in[2];  // [64]
  float* out = (float*)d_out;                 // [64][1][254][254]
  _Float16* ws = (_Float16*)d_ws;             // 10*64*16 f16 = 20,480 B

  weight_prep<<<dim3(1, 1, 1), 256, 0, stream>>>(wgt, bias, ws);
  dim3 grid((OW + TW - 1) / TW, (OH + TH - 1) / TH, 64);  // 8 x 8 x 64
  conv_min_tanh_mfma<<<grid, 256, 0, stream>>>(x, ws, out);
}

// Round 5
// 418.483 us; speedup vs baseline: 1.0877x; 1.0877x over previous
//
#include <hip/hip_runtime.h>

typedef _Float16 f16x8 __attribute__((ext_vector_type(8)));
typedef _Float16 f16x2 __attribute__((ext_vector_type(2)));
typedef float    f32x4 __attribute__((ext_vector_type(4)));

#define CIN    16
#define COUT   64
#define H      256
#define W      256
#define OH     254
#define OW     254
#define TH     32
#define TW     32
#define IN_H   (TH + 2)
#define IN_W   (TW + 2)
#define IN_PIX (IN_H * IN_W)
#define NU     (IN_H * 8 * 9)          // 2448 staging units

// tanh(x) = 1 - 2/(e^{2x}+1): robust at +-inf
__device__ __forceinline__ float ftanh(float x) {
  float e = __expf(x + x);
  float r = __builtin_amdgcn_rcpf(e + 1.0f);
  return 1.0f - (r + r);
}

__device__ __forceinline__ f32x4 vmin4(f32x4 a, f32x4 b) {
  f32x4 r;
  r[0] = fminf(a[0], b[0]); r[1] = fminf(a[1], b[1]);
  r[2] = fminf(a[2], b[2]); r[3] = fminf(a[3], b[3]);
  return r;
}

// ---- one-time weight redistribution into workspace ----
// layout: [tap 0..9][cout 0..63][ci 0..15] f16.
// taps 0..8 = conv weights; tap 9 = bias row: [cout][0] = bias[cout], else 0.
// Matching B-operand for tap-9 k-slots is the register constant {1,0,...,0},
// so bias rides the MFMA and binit[4] (16 AGPRs) disappears.
__global__ __launch_bounds__(256, 1)
void weight_prep(const float* __restrict__ wgt, const float* __restrict__ bias,
                 _Float16* __restrict__ ws) {
  const int t = threadIdx.x;
  // zero tap-9 row: 64*16 f16 = 512 dwords
  uint32_t* wz = (uint32_t*)(ws + 9 * COUT * 16);
  wz[t] = 0u; wz[t + 256] = 0u;
  __syncthreads();
  if (t < COUT) ws[(9 * COUT + t) * 16] = (_Float16)bias[t];
  // coalesced dwordx4 read of [cout][cin][tap] f32, scatter-store as f16
  const f32x4* w4 = (const f32x4*)wgt;   // 9216 floats, 36 per thread
#pragma unroll
  for (int k = 0; k < 9; ++k) {
    const f32x4 v = w4[9 * t + k];
#pragma unroll
    for (int e = 0; e < 4; ++e) {
      const int g   = (9 * t + k) * 4 + e;
      const int co  = g / 144;
      const int r   = g - 144 * co;
      const int ci  = r / 9;
      const int tap = r - 9 * ci;
      ws[(tap * COUT + co) * 16 + ci] = (_Float16)v[e];   // taps 0..8 only
    }
  }
}

__global__ __launch_bounds__(256, 4)
void conv_min_tanh_mfma(const float* __restrict__ x, const _Float16* __restrict__ ws,
                        float* __restrict__ out) {
  // input tile, fp16, interleaved [pixel][cin]: 34*34*16*2 = 36,992 B
  __shared__ __align__(16) _Float16 xs[IN_PIX * CIN];

  const int t   = threadIdx.x;
  const int b   = blockIdx.z;
  const int ow0 = blockIdx.x * TW;
  const int oh0 = blockIdx.y * TH;

  const int lane = t & 63;
  const int ln   = lane & 15;
  const int q    = lane >> 4;
  const int qh   = q >> 1;
  const int ql   = q & 1;

  // ---- A-fragments: 20 x 16B global loads, L2-broadcast ----
  // A[m=cout][k], lane holds cout = mt*16+ln, k = s*32 + q*8 + j,
  // K order: k = tap*16 + ci (tap = kh*3+kw); tap 9 = bias row.
  f16x8 wf[5][4];
#pragma unroll
  for (int s = 0; s < 5; ++s) {
    const int tap = 2 * s + qh;            // 0..9
#pragma unroll
    for (int mt = 0; mt < 4; ++mt) {
      const int cout = mt * 16 + ln;
      wf[s][mt] = *(const f16x8*)(ws + (tap * COUT + cout) * 16 + ql * 8);
    }
  }

  // constant B-frag for the bias k-slots (s=4, qh=1 lanes):
  // q==2 (ci 0..7) -> {1,0,...,0}; q==3 (ci 8..15) -> all zeros.
  f16x8 cst = {};
  if (q == 2) cst[0] = (_Float16)1.0f;

  // ---- stage input tile: depth-3 software pipeline (net-zero regs vs R3:
  // binit's 16 AGPRs were freed by the bias-fold and spent on sv[2]) ----
  // unit u = (row*8 + cp)*9 + j: lane loads 4 consecutive pixels of
  // channels 2cp,2cp+1 (two dwordx4), packs 4 f16x2 -> LDS interleaved.
  {
    f32x4 sv0[3], sv1[3];
    int   sbase[3], sj[3];
    bool  sact[3];

    auto prep = [&](int i, int slot) {
      const int  u   = t + 256 * i;
      const bool act = (u < NU);
      const int  s   = u / 9;
      const int  j   = u - 9 * s;
      const int  row = s >> 3;
      const int  cp  = s & 7;
      const int  ih  = oh0 + row;
      const int  iw0 = ow0 + 4 * j;
      const f32x4 z = {0.f, 0.f, 0.f, 0.f};
      sv0[slot] = z; sv1[slot] = z;
      if (act && ih < H && iw0 + 3 < W) {
        const float* p = x + (((size_t)b * CIN + 2 * cp) * H + ih) * W + iw0;
        sv0[slot] = *(const f32x4*)p;
        sv1[slot] = *(const f32x4*)(p + H * W);
      }
      sbase[slot] = (row * IN_W + 4 * j) * CIN + 2 * cp;
      sj[slot]    = j;
      sact[slot]  = act;
    };
    auto flush = [&](int slot) {
      if (sact[slot]) {
        const int base = sbase[slot];
        const int j    = sj[slot];
#pragma unroll
        for (int e = 0; e < 4; ++e) {
          if (4 * j + e < IN_W) {  // drop cols 34,35 of the j==8 over-read
            f16x2 h;
            h[0] = (_Float16)sv0[slot][e];
            h[1] = (_Float16)sv1[slot][e];
            *(f16x2*)(&xs[base + e * CIN]) = h;
          }
        }
      }
    };

    prep(0, 0);
    prep(1, 1);
    prep(2, 2);
#pragma unroll
    for (int i = 0; i < 10; ++i) {
      flush(i % 3);                                   // wait slot-i loads only
      if (i + 3 < 10) prep(i + 3, (i + 3) % 3);       // keep 3 pairs in flight
    }
  }

  // per-lane LDS element offset per K-step (qh=1 s=4 lanes use cst instead)
  int xoff[5];
#pragma unroll
  for (int s = 0; s < 5; ++s) {
    int tap = 2 * s + qh;
    if (tap > 8) tap = 8;                  // keep address in-bounds (unused)
    const int kh = tap / 3;
    const int kw = tap - kh * 3;
    xoff[s] = (kh * IN_W + kw) * CIN + ql * 8;
  }

  __syncthreads();   // the only barrier: xs staged, compute may read

  // ---- main: each wave does 8 rows x 2 col-tiles of 16 pixels ----
  const int wv = t >> 6;
  for (int rr = 0; rr < 8; ++rr) {
    const int row = wv * 8 + rr;
#pragma unroll
    for (int ct = 0; ct < 2; ++ct) {
      const int base_idx = (row * IN_W + ct * 16 + ln) * CIN;
      f32x4 a0 = {}, a1 = {}, a2 = {}, a3 = {};
#pragma unroll
      for (int s = 0; s < 5; ++s) {
        f16x8 xf;
        if (s == 4 && qh == 1) xf = cst;   // bias k-slots
        else xf = *(const f16x8*)(&xs[base_idx + xoff[s]]);  // ds_read_b128
        a0 = __builtin_amdgcn_mfma_f32_16x16x32_f16(wf[s][0], xf, a0, 0, 0, 0);
        a1 = __builtin_amdgcn_mfma_f32_16x16x32_f16(wf[s][1], xf, a1, 0, 0, 0);
        a2 = __builtin_amdgcn_mfma_f32_16x16x32_f16(wf[s][2], xf, a2, 0, 0, 0);
        a3 = __builtin_amdgcn_mfma_f32_16x16x32_f16(wf[s][3], xf, a3, 0, 0, 0);
      }
      // min over 64 couts: 4 m-tiles x 4 regs in-lane, then across quads
      f32x4 m4 = vmin4(vmin4(a0, a1), vmin4(a2, a3));
      float v = fminf(fminf(m4[0], m4[1]), fminf(m4[2], m4[3]));
      v = fminf(v, __shfl_xor(v, 16));
      v = fminf(v, __shfl_xor(v, 32));
      v = ftanh(ftanh(v));
      const int oh = oh0 + row;
      const int ow = ow0 + ct * 16 + ln;
      if (q == 0 && oh < OH && ow < OW)
        out[((size_t)b * OH + oh) * OW + ow] = v;   // 16 lanes, 64B coalesced
    }
  }
}

extern "C" void kernel_launch(void* const* d_in, const int* in_sizes, int n_in,
                              void* d_out, int out_size, void* d_ws, size_t ws_size,
                              hipStream_t stream) {
  const float* x    = (const float*)d_in[0];
  const float* wgt  = (const float*)d_in[1];  // [64][16][3][3]
  const float* bias = (const float*)d_in[2];  // [64]
  float* out = (float*)d_out;                 // [64][1][254][254]
  _Float16* ws = (_Float16*)d_ws;             // 10*64*16 f16 = 20,480 B

  weight_prep<<<dim3(1, 1, 1), 256, 0, stream>>>(wgt, bias, ws);
  dim3 grid((OW + TW - 1) / TW, (OH + TH - 1) / TH, 64);  // 8 x 8 x 64
  conv_min_tanh_mfma<<<grid, 256, 0, stream>>>(x, ws, out);
}

// Round 6
// 413.861 us; speedup vs baseline: 1.0998x; 1.0112x over previous
//
#include <hip/hip_runtime.h>

typedef _Float16 f16x8 __attribute__((ext_vector_type(8)));
typedef _Float16 f16x2 __attribute__((ext_vector_type(2)));
typedef float    f32x4 __attribute__((ext_vector_type(4)));

#define CIN    16
#define COUT   64
#define H      256
#define W      256
#define OH     254
#define OW     254
#define TH     32
#define TW     32
#define IN_H   (TH + 2)
#define IN_W   (TW + 2)
#define IN_PIX (IN_H * IN_W)
#define NU     (IN_H * 8 * 9)          // 2448 staging units

// LDS bank-conflict swizzle: flip bit4 (16B half-slot) based on bit7
// (pixel bit 2). Reads (16B, pix*32+ql*16) become 2-way (free, m136);
// staging writes (4B, pix*32+cp*4) drop 9-way -> ~5-way. Involution, and
// every access sits wholly inside one 16B half, so write/read agree.
__device__ __forceinline__ int swz(int byt) {
  return byt ^ (((byt >> 7) & 1) << 4);
}

// tanh(x) = 1 - 2/(e^{2x}+1): robust at +-inf
__device__ __forceinline__ float ftanh(float x) {
  float e = __expf(x + x);
  float r = __builtin_amdgcn_rcpf(e + 1.0f);
  return 1.0f - (r + r);
}

__device__ __forceinline__ f32x4 vmin4(f32x4 a, f32x4 b) {
  f32x4 r;
  r[0] = fminf(a[0], b[0]); r[1] = fminf(a[1], b[1]);
  r[2] = fminf(a[2], b[2]); r[3] = fminf(a[3], b[3]);
  return r;
}

// ---- one-time weight redistribution into workspace ----
// layout: [tap 0..9][cout 0..63][ci 0..15] f16.
// taps 0..8 = conv weights; tap 9 = bias row: [cout][0] = bias[cout], else 0.
// Matching B-operand for tap-9 k-slots is the register constant {1,0,...,0},
// so bias rides the MFMA and binit[4] (16 AGPRs) disappears.
__global__ __launch_bounds__(256, 1)
void weight_prep(const float* __restrict__ wgt, const float* __restrict__ bias,
                 _Float16* __restrict__ ws) {
  const int t = threadIdx.x;
  // zero tap-9 row: 64*16 f16 = 512 dwords
  uint32_t* wz = (uint32_t*)(ws + 9 * COUT * 16);
  wz[t] = 0u; wz[t + 256] = 0u;
  __syncthreads();
  if (t < COUT) ws[(9 * COUT + t) * 16] = (_Float16)bias[t];
  // coalesced dwordx4 read of [cout][cin][tap] f32, scatter-store as f16
  const f32x4* w4 = (const f32x4*)wgt;   // 9216 floats, 36 per thread
#pragma unroll
  for (int k = 0; k < 9; ++k) {
    const f32x4 v = w4[9 * t + k];
#pragma unroll
    for (int e = 0; e < 4; ++e) {
      const int g   = (9 * t + k) * 4 + e;
      const int co  = g / 144;
      const int r   = g - 144 * co;
      const int ci  = r / 9;
      const int tap = r - 9 * ci;
      ws[(tap * COUT + co) * 16 + ci] = (_Float16)v[e];   // taps 0..8 only
    }
  }
}

__global__ __launch_bounds__(256, 4)
void conv_min_tanh_mfma(const float* __restrict__ x, const _Float16* __restrict__ ws,
                        float* __restrict__ out) {
  // input tile, fp16, interleaved [pixel][cin], XOR-swizzled: 36,992 B
  __shared__ __align__(16) _Float16 xs[IN_PIX * CIN];

  const int t   = threadIdx.x;
  const int b   = blockIdx.z;
  const int ow0 = blockIdx.x * TW;
  const int oh0 = blockIdx.y * TH;

  const int lane = t & 63;
  const int ln   = lane & 15;
  const int q    = lane >> 4;
  const int qh   = q >> 1;
  const int ql   = q & 1;

  // ---- A-fragments: 20 x 16B global loads, L2-broadcast ----
  // A[m=cout][k], lane holds cout = mt*16+ln, k = s*32 + q*8 + j,
  // K order: k = tap*16 + ci (tap = kh*3+kw); tap 9 = bias row.
  f16x8 wf[5][4];
#pragma unroll
  for (int s = 0; s < 5; ++s) {
    const int tap = 2 * s + qh;            // 0..9
#pragma unroll
    for (int mt = 0; mt < 4; ++mt) {
      const int cout = mt * 16 + ln;
      wf[s][mt] = *(const f16x8*)(ws + (tap * COUT + cout) * 16 + ql * 8);
    }
  }

  // constant B-frag for the bias k-slots (s=4, qh=1 lanes):
  // q==2 (ci 0..7) -> {1,0,...,0}; q==3 (ci 8..15) -> all zeros.
  f16x8 cst = {};
  if (q == 2) cst[0] = (_Float16)1.0f;

  // ---- stage input tile: depth-3 software pipeline ----
  // unit u = (row*8 + cp)*9 + j: lane loads 4 consecutive pixels of
  // channels 2cp,2cp+1 (two dwordx4), packs 4 f16x2 -> LDS (swizzled).
  {
    f32x4 sv0[3], sv1[3];
    int   sbase[3], sj[3];
    bool  sact[3];

    auto prep = [&](int i, int slot) {
      const int  u   = t + 256 * i;
      const bool act = (u < NU);
      const int  s   = u / 9;
      const int  j   = u - 9 * s;
      const int  row = s >> 3;
      const int  cp  = s & 7;
      const int  ih  = oh0 + row;
      const int  iw0 = ow0 + 4 * j;
      const f32x4 z = {0.f, 0.f, 0.f, 0.f};
      sv0[slot] = z; sv1[slot] = z;
      if (act && ih < H && iw0 + 3 < W) {
        const float* p = x + (((size_t)b * CIN + 2 * cp) * H + ih) * W + iw0;
        sv0[slot] = *(const f32x4*)p;
        sv1[slot] = *(const f32x4*)(p + H * W);
      }
      sbase[slot] = (row * IN_W + 4 * j) * CIN + 2 * cp;
      sj[slot]    = j;
      sact[slot]  = act;
    };
    auto flush = [&](int slot) {
      if (sact[slot]) {
        const int base = sbase[slot];
        const int j    = sj[slot];
#pragma unroll
        for (int e = 0; e < 4; ++e) {
          if (4 * j + e < IN_W) {  // drop cols 34,35 of the j==8 over-read
            f16x2 h;
            h[0] = (_Float16)sv0[slot][e];
            h[1] = (_Float16)sv1[slot][e];
            *(f16x2*)((char*)xs + swz((base + e * CIN) * 2)) = h;
          }
        }
      }
    };

    prep(0, 0);
    prep(1, 1);
    prep(2, 2);
#pragma unroll
    for (int i = 0; i < 10; ++i) {
      flush(i % 3);                                   // wait slot-i loads only
      if (i + 3 < 10) prep(i + 3, (i + 3) % 3);       // keep 3 pairs in flight
    }
  }

  // per-lane LDS element offset per K-step (qh=1 s=4 lanes use cst instead)
  int xoff[5];
#pragma unroll
  for (int s = 0; s < 5; ++s) {
    int tap = 2 * s + qh;
    if (tap > 8) tap = 8;                  // keep address in-bounds (unused)
    const int kh = tap / 3;
    const int kw = tap - kh * 3;
    xoff[s] = (kh * IN_W + kw) * CIN + ql * 8;
  }

  __syncthreads();   // the only barrier: xs staged, compute may read

  // ---- main: each wave does 8 rows x 2 col-tiles of 16 pixels ----
  const int wv = t >> 6;
  for (int rr = 0; rr < 8; ++rr) {
    const int row = wv * 8 + rr;
    float vout[2];
#pragma unroll
    for (int ct = 0; ct < 2; ++ct) {
      const int base_idx = (row * IN_W + ct * 16 + ln) * CIN;
      f32x4 a0 = {}, a1 = {}, a2 = {}, a3 = {};
#pragma unroll
      for (int s = 0; s < 5; ++s) {
        f16x8 xf;
        if (s == 4 && qh == 1) xf = cst;   // bias k-slots
        else xf = *(const f16x8*)((const char*)xs +
                                  swz((base_idx + xoff[s]) * 2));  // ds_read_b128
        a0 = __builtin_amdgcn_mfma_f32_16x16x32_f16(wf[s][0], xf, a0, 0, 0, 0);
        a1 = __builtin_amdgcn_mfma_f32_16x16x32_f16(wf[s][1], xf, a1, 0, 0, 0);
        a2 = __builtin_amdgcn_mfma_f32_16x16x32_f16(wf[s][2], xf, a2, 0, 0, 0);
        a3 = __builtin_amdgcn_mfma_f32_16x16x32_f16(wf[s][3], xf, a3, 0, 0, 0);
      }
      // min over 64 couts: 4 m-tiles x 4 regs in-lane, then across quads
      f32x4 m4 = vmin4(vmin4(a0, a1), vmin4(a2, a3));
      float v = fminf(fminf(m4[0], m4[1]), fminf(m4[2], m4[3]));
      v = fminf(v, __shfl_xor(v, 16));
      v = fminf(v, __shfl_xor(v, 32));
      vout[ct] = ftanh(ftanh(v));
    }
    // coalesced store: lanes q=0 (ct 0) and q=1 (ct 1) -> one 128B span
    const int oh = oh0 + row;
    const int ow = ow0 + q * 16 + ln;
    if (q < 2 && oh < OH && ow < OW)
      out[((size_t)b * OH + oh) * OW + ow] = (q == 0) ? vout[0] : vout[1];
  }
}

extern "C" void kernel_launch(void* const* d_in, const int* in_sizes, int n_in,
                              void* d_out, int out_size, void* d_ws, size_t ws_size,
                              hipStream_t stream) {
  const float* x    = (const float*)d_in[0];
  const float* wgt  = (const float*)d_in[1];  // [64][16][3][3]
  const float* bias = (const float*)d_in[2];  // [64]
  float* out = (float*)d_out;                 // [64][1][254][254]
  _Float16* ws = (_Float16*)d_ws;             // 10*64*16 f16 = 20,480 B

  weight_prep<<<dim3(1, 1, 1), 256, 0, stream>>>(wgt, bias, ws);
  dim3 grid((OW + TW - 1) / TW, (OH + TH - 1) / TH, 64);  // 8 x 8 x 64
  conv_min_tanh_mfma<<<grid, 256, 0, stream>>>(x, ws, out);
}

// Round 7
// 391.428 us; speedup vs baseline: 1.1628x; 1.0573x over previous
//
#include <hip/hip_runtime.h>

typedef _Float16 f16x8 __attribute__((ext_vector_type(8)));
typedef _Float16 f16x2 __attribute__((ext_vector_type(2)));
typedef float    f32x4 __attribute__((ext_vector_type(4)));
typedef float    f32x16 __attribute__((ext_vector_type(16)));

#define CIN    16
#define COUT   64
#define H      256
#define W      256
#define OH     254
#define OW     254
#define TH     32
#define TW     32
#define IN_H   (TH + 2)
#define IN_W   (TW + 2)
#define IN_PIX (IN_H * IN_W)
#define NU     (IN_H * 8 * 9)          // 2448 staging units

// tanh(x) = 1 - 2/(e^{2x}+1): robust at +-inf
__device__ __forceinline__ float ftanh(float x) {
  float e = __expf(x + x);
  float r = __builtin_amdgcn_rcpf(e + 1.0f);
  return 1.0f - (r + r);
}

__device__ __forceinline__ f32x4 vmin4(f32x4 a, f32x4 b) {
  f32x4 r;
  r[0] = fminf(a[0], b[0]); r[1] = fminf(a[1], b[1]);
  r[2] = fminf(a[2], b[2]); r[3] = fminf(a[3], b[3]);
  return r;
}

// min over the 16 C/D regs of a 32x32 MFMA (16 couts held in-lane).
// Row->cout permutation is irrelevant: we reduce over all of them.
__device__ __forceinline__ float rmin16(const f32x16& A) {
  f32x4 a = {A[0], A[1], A[2], A[3]};
  f32x4 b = {A[4], A[5], A[6], A[7]};
  f32x4 c = {A[8], A[9], A[10], A[11]};
  f32x4 d = {A[12], A[13], A[14], A[15]};
  f32x4 m = vmin4(vmin4(a, b), vmin4(c, d));
  return fminf(fminf(m[0], m[1]), fminf(m[2], m[3]));
}

// ---- one-time weight redistribution into workspace ----
// layout: [tap 0..9][cout 0..63][ci 0..15] f16.
// taps 0..8 = conv weights; tap 9 = bias row: [cout][0] = bias[cout], else 0.
// Matching B-operand for tap-9 is the register constant {1,0,...,0}.
__global__ __launch_bounds__(256, 1)
void weight_prep(const float* __restrict__ wgt, const float* __restrict__ bias,
                 _Float16* __restrict__ ws) {
  const int t = threadIdx.x;
  // zero tap-9 row: 64*16 f16 = 512 dwords
  uint32_t* wz = (uint32_t*)(ws + 9 * COUT * 16);
  wz[t] = 0u; wz[t + 256] = 0u;
  __syncthreads();
  if (t < COUT) ws[(9 * COUT + t) * 16] = (_Float16)bias[t];
  // coalesced dwordx4 read of [cout][cin][tap] f32, scatter-store as f16
  const f32x4* w4 = (const f32x4*)wgt;   // 9216 floats, 36 per thread
#pragma unroll
  for (int k = 0; k < 9; ++k) {
    const f32x4 v = w4[9 * t + k];
#pragma unroll
    for (int e = 0; e < 4; ++e) {
      const int g   = (9 * t + k) * 4 + e;
      const int co  = g / 144;
      const int r   = g - 144 * co;
      const int ci  = r / 9;
      const int tap = r - 9 * ci;
      ws[(tap * COUT + co) * 16 + ci] = (_Float16)v[e];   // taps 0..8 only
    }
  }
}

__global__ __launch_bounds__(256, 4)
void conv_min_tanh_mfma(const float* __restrict__ x, const _Float16* __restrict__ ws,
                        float* __restrict__ out) {
  // input tile, fp16, interleaved [pixel][ci], LINEAR (32x32 MFMA read
  // pattern is inherently bank-balanced: 64 lanes x 16B at 32B stride
  // cover all 32 banks x 8 requests exactly).
  __shared__ __align__(16) _Float16 xs[IN_PIX * CIN];
  // cout-half min scratch: [ch][16 phase-rows][32 cols] f16 = 2 KB.
  // Total LDS 39,040 B -> 4 blocks/CU.
  __shared__ _Float16 sm[2][16][32];

  const int t   = threadIdx.x;
  const int b   = blockIdx.z;
  const int ow0 = blockIdx.x * TW;
  const int oh0 = blockIdx.y * TH;

  const int lane = t & 63;
  const int n32  = lane & 31;   // pixel column / cout-within-half / out col
  const int hl   = lane >> 5;   // k-half (ci 0..7 vs 8..15)
  const int wv   = t >> 6;
  const int ch   = wv & 1;      // cout half (0: couts 0..31, 1: 32..63)
  const int pr   = wv >> 1;     // row strip (0: rows 0..15, 1: 16..31)

  // ---- A-fragments: 10 taps x 16B global loads, L2-broadcast ----
  // 32x32x16 A[m][k]: m = ch*32 + n32 (cout), k = hl*8 + j (ci). 40 regs.
  f16x8 wf[10];
#pragma unroll
  for (int tp = 0; tp < 10; ++tp)
    wf[tp] = *(const f16x8*)(ws + (tp * COUT + ch * 32 + n32) * 16 + hl * 8);

  // constant B-frag for the bias tap: k=0 (= hl 0, j 0) is 1, rest 0.
  f16x8 cst = {};
  if (hl == 0) cst[0] = (_Float16)1.0f;

  // ---- stage input tile: depth-3 software pipeline (unchanged scheme) ----
  // unit u = (row*8 + cp)*9 + j: lane loads 4 consecutive pixels of
  // channels 2cp,2cp+1 (two dwordx4), packs 4 f16x2 -> LDS interleaved.
  {
    f32x4 sv0[3], sv1[3];
    int   sbase[3], sj[3];
    bool  sact[3];

    auto prep = [&](int i, int slot) {
      const int  u   = t + 256 * i;
      const bool act = (u < NU);
      const int  s   = u / 9;
      const int  j   = u - 9 * s;
      const int  row = s >> 3;
      const int  cp  = s & 7;
      const int  ih  = oh0 + row;
      const int  iw0 = ow0 + 4 * j;
      const f32x4 z = {0.f, 0.f, 0.f, 0.f};
      sv0[slot] = z; sv1[slot] = z;
      if (act && ih < H && iw0 + 3 < W) {
        const float* p = x + (((size_t)b * CIN + 2 * cp) * H + ih) * W + iw0;
        sv0[slot] = *(const f32x4*)p;
        sv1[slot] = *(const f32x4*)(p + H * W);
      }
      sbase[slot] = (row * IN_W + 4 * j) * CIN + 2 * cp;
      sj[slot]    = j;
      sact[slot]  = act;
    };
    auto flush = [&](int slot) {
      if (sact[slot]) {
        const int base = sbase[slot];
        const int j    = sj[slot];
#pragma unroll
        for (int e = 0; e < 4; ++e) {
          if (4 * j + e < IN_W) {  // drop cols 34,35 of the j==8 over-read
            f16x2 h;
            h[0] = (_Float16)sv0[slot][e];
            h[1] = (_Float16)sv1[slot][e];
            *(f16x2*)(&xs[base + e * CIN]) = h;
          }
        }
      }
    };

    prep(0, 0);
    prep(1, 1);
    prep(2, 2);
#pragma unroll
    for (int i = 0; i < 10; ++i) {
      flush(i % 3);                                   // wait slot-i loads only
      if (i + 3 < 10) prep(i + 3, (i + 3) % 3);       // keep 3 pairs in flight
    }
  }

  __syncthreads();   // xs staged

  // ---- compute: 2 phases x 4 row-pairs; each MFMA covers the full 32-col
  // tile (N=32) and 32 couts (this wave's half), K=16 = one tap x all ci.
  for (int ph = 0; ph < 2; ++ph) {
#pragma unroll
    for (int rp = 0; rp < 4; ++rp) {
      const int r0 = pr * 16 + ph * 8 + rp * 2;     // two output rows
      // B-frag base: pixel (r, n32), ci-half hl; taps via offset: immediates
      const _Float16* p0 = xs + (r0 * IN_W + n32) * CIN + hl * 8;
      const _Float16* p1 = p0 + IN_W * CIN;
      f32x16 A0 = {}, A1 = {};
#pragma unroll
      for (int tp = 0; tp < 9; ++tp) {
        const int off = ((tp / 3) * IN_W + (tp % 3)) * CIN;
        f16x8 x0 = *(const f16x8*)(p0 + off);       // ds_read_b128 offset:
        f16x8 x1 = *(const f16x8*)(p1 + off);
        A0 = __builtin_amdgcn_mfma_f32_32x32x16_f16(wf[tp], x0, A0, 0, 0, 0);
        A1 = __builtin_amdgcn_mfma_f32_32x32x16_f16(wf[tp], x1, A1, 0, 0, 0);
      }
      A0 = __builtin_amdgcn_mfma_f32_32x32x16_f16(wf[9], cst, A0, 0, 0, 0);
      A1 = __builtin_amdgcn_mfma_f32_32x32x16_f16(wf[9], cst, A1, 0, 0, 0);
      // min over this wave's 32 couts: 16 in-lane + lane<->lane+32
      float v0 = rmin16(A0), v1 = rmin16(A1);
      v0 = fminf(v0, __shfl_xor(v0, 32));
      v1 = fminf(v1, __shfl_xor(v1, 32));
      if (lane < 32) {
        sm[ch][pr * 8 + rp * 2 + 0][lane] = (_Float16)v0;
        sm[ch][pr * 8 + rp * 2 + 1][lane] = (_Float16)v1;
      }
    }
    __syncthreads();   // all 16 phase-rows x both halves in sm

    // combine: wave wv handles scratch rows wv*4 .. wv*4+3 (2 per lane-half)
#pragma unroll
    for (int k2 = 0; k2 < 2; ++k2) {
      const int r = wv * 4 + hl * 2 + k2;           // scratch row 0..15
      const float s0 = (float)sm[0][r][n32];
      const float s1 = (float)sm[1][r][n32];
      const float v  = ftanh(ftanh(fminf(s0, s1)));
      const int orow = (r >> 3) * 16 + ph * 8 + (r & 7);
      const int oh = oh0 + orow;
      const int ow = ow0 + n32;
      if (oh < OH && ow < OW)
        out[((size_t)b * OH + oh) * OW + ow] = v;   // 32 lanes, 128B spans
    }
    __syncthreads();   // sm readers done before next phase overwrites
  }
}

extern "C" void kernel_launch(void* const* d_in, const int* in_sizes, int n_in,
                              void* d_out, int out_size, void* d_ws, size_t ws_size,
                              hipStream_t stream) {
  const float* x    = (const float*)d_in[0];
  const float* wgt  = (const float*)d_in[1];  // [64][16][3][3]
  const float* bias = (const float*)d_in[2];  // [64]
  float* out = (float*)d_out;                 // [64][1][254][254]
  _Float16* ws = (_Float16*)d_ws;             // 10*64*16 f16 = 20,480 B

  weight_prep<<<dim3(1, 1, 1), 256, 0, stream>>>(wgt, bias, ws);
  dim3 grid((OW + TW - 1) / TW, (OH + TH - 1) / TH, 64);  // 8 x 8 x 64
  conv_min_tanh_mfma<<<grid, 256, 0, stream>>>(x, ws, out);
}